// Round 17
// baseline (11963.469 us; speedup 1.0000x reference)
//
#include <hip/hip_runtime.h>
#include <stdint.h>

#define TT 2048
#define HH 256
#define BB 128

typedef __attribute__((ext_vector_type(8))) short short8;   // 8 x bf16 (4 VGPRs)
typedef __attribute__((ext_vector_type(4))) float f32x4;    // 4 x f32 acc

__device__ __forceinline__ unsigned short f2bf(float f) {
  union { float f; unsigned int u; } v; v.f = f;
  unsigned int r = v.u + 0x7fffu + ((v.u >> 16) & 1u);   // RNE
  return (unsigned short)(r >> 16);
}
__device__ __forceinline__ float sigm(float x) { return 1.0f / (1.0f + __expf(-x)); }
__device__ __forceinline__ float tanh_f(float x) { return 1.0f - 2.0f / (1.0f + __expf(2.0f * x)); }

// MFMA, B pinned to AGPR (recurrent weights) / VGPR (input weights)
__device__ __forceinline__ void mfma_a(f32x4& acc, short8 a, short8 b) {
  asm("v_mfma_f32_16x16x32_bf16 %0, %1, %2, %0" : "+v"(acc) : "v"(a), "a"(b));
}
__device__ __forceinline__ void mfma_v(f32x4& acc, short8 a, short8 b) {
  asm("v_mfma_f32_16x16x32_bf16 %0, %1, %2, %0" : "+v"(acc) : "v"(a), "v"(b));
}
// IC-coherent accesses (round-4/9/12/14 proven primitives)
__device__ __forceinline__ short8 ld16_ic(const unsigned short* p) {
  union { unsigned long long q[2]; short8 v; } u;
  u.q[0] = __hip_atomic_load((const unsigned long long*)p, __ATOMIC_RELAXED, __HIP_MEMORY_SCOPE_AGENT);
  u.q[1] = __hip_atomic_load(((const unsigned long long*)p) + 1, __ATOMIC_RELAXED, __HIP_MEMORY_SCOPE_AGENT);
  return u.v;
}
__device__ __forceinline__ void st2_ic(unsigned short* p, unsigned short v) {
  unsigned int vv = v;
  asm volatile("global_store_short %0, %1, off sc0 sc1" :: "v"(p), "v"(vv) : "memory");
}
#define POLL(dst, ptr) \
  asm volatile("global_load_dword %0, %1, off sc0 sc1" : "=v"(dst) : "v"(ptr) : "memory")
// full drain: everything retired under ANY vmcnt retirement semantics
#define VMW0() \
  do { asm volatile("s_waitcnt vmcnt(0)" ::: "memory"); \
       __builtin_amdgcn_sched_barrier(0); } while (0)
// partial drain: safe ONLY when the vmcnt queue contains loads exclusively (m135)
#define VMW1() \
  do { asm volatile("s_waitcnt vmcnt(1)" ::: "memory"); \
       __builtin_amdgcn_sched_barrier(0); } while (0)
// sleep-throttled wave-collective flag wait (round-12-proven; used at t=0 only)
__device__ __forceinline__ void waitN(int* f, int idx, int tgt) {
  for (;;) {
    int v = __hip_atomic_load(&f[idx * 16], __ATOMIC_RELAXED, __HIP_MEMORY_SCOPE_AGENT);
    if (__all(v >= tgt)) break;
    __builtin_amdgcn_s_sleep(1);
  }
}

// ---------------- prep: weight bf16 conversion, bias sums, zero flags ----------------
__global__ void prep_kernel(const float* __restrict__ whh0, const float* __restrict__ wih1,
                            const float* __restrict__ whh1,
                            const float* __restrict__ bih0, const float* __restrict__ bhh0,
                            const float* __restrict__ bih1, const float* __restrict__ bhh1,
                            unsigned short* __restrict__ whh0b, unsigned short* __restrict__ wih1b,
                            unsigned short* __restrict__ whh1b,
                            float* __restrict__ bsum0, float* __restrict__ bsum1,
                            int* __restrict__ flags) {
  int i = blockIdx.x * blockDim.x + threadIdx.x;   // 262144 threads exactly
  if (i < 262144) {
    whh0b[i] = f2bf(whh0[i]);
    wih1b[i] = f2bf(wih1[i]);
    whh1b[i] = f2bf(whh1[i]);
  }
  if (i < 1024) bsum0[i] = bih0[i] + bhh0[i];
  else if (i < 2048) { int j = i - 1024; bsum1[j] = bih1[j] + bhh1[j]; }
  if (i < 8192) flags[i] = 0;
}

// ---------------- fused 2-layer pipeline, quarter-split, per-WAVE flags ----------------
// ROUND-16 byte-for-byte (protocol, flags, targets, rings, arithmetic, spec-poll tail),
// with ONE mechanics delta: the miss path is a 2-in-flight pipelined poll (attempt
// rate 1/RTT) instead of the sleep-throttled single poll. Runs only after the tail's
// full VMW0 => vmcnt queue holds LOADS ONLY (m135 in-order) — r15's mixed-queue hazard
// cannot occur. Dangling poll after success is absorbed by the data-load waits.
__attribute__((amdgpu_flat_work_group_size(256, 256)))
__attribute__((amdgpu_waves_per_eu(1, 1)))
__global__ void rec_all(
    const float* __restrict__ x,
    const unsigned short* __restrict__ whh0b, const float* __restrict__ wih0,
    const float* __restrict__ bsum0,
    const unsigned short* __restrict__ wih1b,
    const unsigned short* __restrict__ whh1b, const float* __restrict__ bsum1,
    const int* __restrict__ lengths,
    float* __restrict__ pooled,
    unsigned short* __restrict__ h1ring,   // [16][128][256] bf16
    unsigned short* __restrict__ h2ring,   // [2][128][256] bf16
    int* flags)
{
  const int tid = threadIdx.x;
  const int lane = tid & 63;
  const int w = tid >> 6;                  // 0..3
  const int l15 = lane & 15, l4 = lane >> 4;
  const int isL1 = (blockIdx.x >= 32);
  const int wg = blockIdx.x & 31;
  const int q = wg >> 3;
  const int bg = wg & 7;
  const int b0 = bg * 16;
  const int unit = q * 64 + w * 16 + l15;
  const int myfid = (int)blockIdx.x * 4 + w;

  // recurrent weights (AGPR): rows gt*256+unit, K-cols kk*32+l4*8
  const unsigned short* WH = isL1 ? whh1b : whh0b;
  short8 wfh[4][8];
#pragma unroll
  for (int gt = 0; gt < 4; ++gt)
#pragma unroll
    for (int kk = 0; kk < 8; ++kk)
      wfh[gt][kk] = *(const short8*)(WH + (size_t)(gt * 256 + unit) * 256 + kk * 32 + l4 * 8);
  // input weights for L1 (VGPR)
  short8 wfi[4][8];
  if (isL1) {
#pragma unroll
    for (int gt = 0; gt < 4; ++gt)
#pragma unroll
      for (int kk = 0; kk < 8; ++kk)
        wfi[gt][kk] = *(const short8*)(wih1b + (size_t)(gt * 256 + unit) * 256 + kk * 32 + l4 * 8);
  }
  float bs_l[4], wih0_l[4];
#pragma unroll
  for (int gt = 0; gt < 4; ++gt) {
    bs_l[gt] = (isL1 ? bsum1 : bsum0)[gt * 256 + unit];
    wih0_l[gt] = isL1 ? 0.0f : wih0[gt * 256 + unit];
  }

  float c_[4] = {0.f, 0.f, 0.f, 0.f};
  float psum[4] = {0.f, 0.f, 0.f, 0.f};
  int len_[4];
#pragma unroll
  for (int r = 0; r < 4; ++r) len_[r] = lengths[b0 + l4 * 4 + r];

  // loop-carried wait descriptor for step t (initialized for t=0) + speculative state
  int sidx = myfid, stgt = 0, pa = 0, pb = 0;
  bool hit = true;
  if (isL1) {
    if (lane < 16) { sidx = ((lane >> 2) * 8 + bg) * 4 + (lane & 3); stgt = 1; }  // h1(0)
    hit = false;
  }

  for (int t = 0; t < TT; ++t) {
    // ---- wait for step-t deps (skipped when the speculative poll already hit) ----
    if (!hit) {
      if (t == 0) {
        waitN(flags, sidx, stgt);          // cold start: sleep-throttled
      } else {
        // 2-in-flight pipelined poll; queue holds loads only (tail did VMW0)
        const int* pp = &flags[sidx * 16];
        POLL(pa, pp); POLL(pb, pp);
        for (;;) {
          VMW1();                          // pa retired (pb in flight)
          if (__all(pa >= stgt)) break;    // pb dangles into the data loads
          POLL(pa, pp);
          VMW1();                          // pb retired (pa in flight)
          if (__all(pb >= stgt)) break;    // pa dangles
          POLL(pb, pp);
        }
      }
    }

    f32x4 z = {0.f, 0.f, 0.f, 0.f};
    f32x4 acc[4];
#pragma unroll
    for (int gt = 0; gt < 4; ++gt) acc[gt] = z;

    if (!isL1) {
      if (t > 0) {
        const unsigned short* hrow = h1ring + ((size_t)((t - 1) & 15) * BB + b0 + l15) * HH;
        short8 af[8];
#pragma unroll
        for (int kk = 0; kk < 8; ++kk) af[kk] = ld16_ic(hrow + kk * 32 + l4 * 8);
#pragma unroll
        for (int gt = 0; gt < 4; ++gt)
#pragma unroll
          for (int kk = 0; kk < 8; ++kk) mfma_a(acc[gt], af[kk], wfh[gt][kk]);
      }
#pragma unroll
      for (int r = 0; r < 4; ++r) {
        const int sr = l4 * 4 + r;
        const float xv = x[(size_t)(b0 + sr) * TT + t];
        float pi = acc[0][r] + bs_l[0] + xv * wih0_l[0];
        float pf = acc[1][r] + bs_l[1] + xv * wih0_l[1];
        float pg = acc[2][r] + bs_l[2] + xv * wih0_l[2];
        float po = acc[3][r] + bs_l[3] + xv * wih0_l[3];
        const float ig = sigm(pi), fg = sigm(pf), gg = tanh_f(pg), og = sigm(po);
        const float cn = fg * c_[r] + ig * gg;
        c_[r] = cn;
        const float hn = og * tanh_f(cn);
        st2_ic(&h1ring[((size_t)(t & 15) * BB + b0 + sr) * HH + unit], f2bf(hn));
      }
    } else {
      // ---- both batch loads issued together (one serialized RTT) ----
      short8 af1[8], af2[8];
      {
        const unsigned short* h1row = h1ring + ((size_t)(t & 15) * BB + b0 + l15) * HH;
#pragma unroll
        for (int kk = 0; kk < 8; ++kk) af1[kk] = ld16_ic(h1row + kk * 32 + l4 * 8);
      }
      if (t > 0) {
        const unsigned short* h2row = h2ring + ((size_t)((t - 1) & 1) * BB + b0 + l15) * HH;
#pragma unroll
        for (int kk = 0; kk < 8; ++kk) af2[kk] = ld16_ic(h2row + kk * 32 + l4 * 8);
      }
#pragma unroll
      for (int gt = 0; gt < 4; ++gt)
#pragma unroll
        for (int kk = 0; kk < 8; ++kk) mfma_v(acc[gt], af1[kk], wfi[gt][kk]);
      if (t > 0) {
#pragma unroll
        for (int gt = 0; gt < 4; ++gt)
#pragma unroll
          for (int kk = 0; kk < 8; ++kk) mfma_a(acc[gt], af2[kk], wfh[gt][kk]);
      }
#pragma unroll
      for (int r = 0; r < 4; ++r) {
        const int sr = l4 * 4 + r;
        float pi = acc[0][r] + bs_l[0];
        float pf = acc[1][r] + bs_l[1];
        float pg = acc[2][r] + bs_l[2];
        float po = acc[3][r] + bs_l[3];
        const float ig = sigm(pi), fg = sigm(pf), gg = tanh_f(pg), og = sigm(po);
        const float cn = fg * c_[r] + ig * gg;
        c_[r] = cn;
        const float hn = og * tanh_f(cn);
        st2_ic(&h2ring[((size_t)(t & 1) * BB + b0 + sr) * HH + unit], f2bf(hn));
        if (t < len_[r]) psum[r] += hn;
      }
    }

    // ---- tail: speculative poll + FULL drain + publish + hit check ----
    {
      const int s = t + 1;
      sidx = myfid; stgt = 0;
      if (s < TT) {
        if (!isL1) {
          if (lane < 16) { sidx = ((lane >> 2) * 8 + bg) * 4 + (lane & 3); stgt = s; }      // h1(s-1)
          else if (lane < 32) {
            if (s >= 16 && (s & 7) == 0) {                                                  // ring credit (depth 16)
              sidx = 128 + (((lane - 16) >> 2) * 8 + bg) * 4 + (lane & 3); stgt = s - 8;
            }
          }
        } else {
          if (lane < 16) { sidx = ((lane >> 2) * 8 + bg) * 4 + (lane & 3); stgt = s + 1; }  // h1(s)
          else if (lane < 32) { sidx = 128 + (((lane - 16) >> 2) * 8 + bg) * 4 + (lane & 3); stgt = s; } // h2(s-1)
        }
      }
      POLL(pa, &flags[sidx * 16]);   // overlaps the store drain
      VMW0();                        // 4 data stores drained AND poll retired (any semantics)
      if (lane == 0)
        __hip_atomic_store(&flags[myfid * 16], s, __ATOMIC_RELAXED, __HIP_MEMORY_SCOPE_AGENT);
      hit = __all(pa >= stgt);
    }
  }

  if (isL1) {
#pragma unroll
    for (int r = 0; r < 4; ++r)
      pooled[(size_t)(b0 + l4 * 4 + r) * HH + unit] = psum[r];
  }
}

// ---------------- epilogue: apply 1/len and linear head ----------------
__global__ void out_kernel(const float* __restrict__ pooled, const int* __restrict__ lengths,
                           const float* __restrict__ wlin, const float* __restrict__ blin,
                           float* __restrict__ out) {
  const int b = blockIdx.x;
  const int lane = threadIdx.x;   // 64
  float s[7];
#pragma unroll
  for (int c = 0; c < 7; ++c) s[c] = 0.f;
  for (int k = lane; k < 256; k += 64) {
    const float pv = pooled[b * 256 + k];
#pragma unroll
    for (int c = 0; c < 7; ++c) s[c] += pv * wlin[c * 256 + k];
  }
#pragma unroll
  for (int c = 0; c < 7; ++c) {
#pragma unroll
    for (int off = 32; off > 0; off >>= 1) s[c] += __shfl_down(s[c], off);
  }
  if (lane == 0) {
    const float inv = 1.0f / (float)lengths[b];
#pragma unroll
    for (int c = 0; c < 7; ++c) out[b * 7 + c] = s[c] * inv + blin[c];
  }
}

extern "C" void kernel_launch(void* const* d_in, const int* in_sizes, int n_in,
                              void* d_out, int out_size, void* d_ws, size_t ws_size,
                              hipStream_t stream) {
  const float* x      = (const float*)d_in[0];
  const int*   lengths= (const int*)d_in[1];
  const float* W_ih0  = (const float*)d_in[2];
  const float* W_hh0  = (const float*)d_in[3];
  const float* b_ih0  = (const float*)d_in[4];
  const float* b_hh0  = (const float*)d_in[5];
  const float* W_ih1  = (const float*)d_in[6];
  const float* W_hh1  = (const float*)d_in[7];
  const float* b_ih1  = (const float*)d_in[8];
  const float* b_hh1  = (const float*)d_in[9];
  const float* W_lin  = (const float*)d_in[10];
  const float* b_lin  = (const float*)d_in[11];
  float* out = (float*)d_out;

  char* ws = (char*)d_ws;
  unsigned short* whh0b = (unsigned short*)(ws + 0);
  unsigned short* wih1b = (unsigned short*)(ws + 524288);
  unsigned short* whh1b = (unsigned short*)(ws + 1048576);
  float* bsum0   = (float*)(ws + 1572864);
  float* bsum1   = (float*)(ws + 1576960);
  int*   flags   = (int*)  (ws + 1581056);                    // 8192 ints (padded flags)
  float* pooled  = (float*)(ws + 1613824);                    // 128KB
  unsigned short* h2ring = (unsigned short*)(ws + 1744896);   // 128KB (depth 2)
  unsigned short* h1ring = (unsigned short*)(ws + 1875968);   // 1MB (depth 16)

  prep_kernel<<<dim3(1024), dim3(256), 0, stream>>>(
      W_hh0, W_ih1, W_hh1, b_ih0, b_hh0, b_ih1, b_hh1,
      whh0b, wih1b, whh1b, bsum0, bsum1, flags);

  rec_all<<<dim3(64), dim3(256), 0, stream>>>(
      x, whh0b, W_ih0, bsum0, wih1b, whh1b, bsum1, lengths,
      pooled, h1ring, h2ring, flags);

  out_kernel<<<dim3(128), dim3(64), 0, stream>>>(pooled, lengths, W_lin, b_lin, out);
}

// Round 18
// 11343.781 us; speedup vs baseline: 1.0546x; 1.0546x over previous
//
#include <hip/hip_runtime.h>
#include <stdint.h>

#define TT 2048
#define HH 256
#define BB 128

typedef __attribute__((ext_vector_type(8))) short short8;   // 8 x bf16 (4 VGPRs)
typedef __attribute__((ext_vector_type(4))) float f32x4;    // 4 x f32 acc

__device__ __forceinline__ unsigned short f2bf(float f) {
  union { float f; unsigned int u; } v; v.f = f;
  unsigned int r = v.u + 0x7fffu + ((v.u >> 16) & 1u);   // RNE
  return (unsigned short)(r >> 16);
}
__device__ __forceinline__ float sigm(float x) { return 1.0f / (1.0f + __expf(-x)); }
__device__ __forceinline__ float tanh_f(float x) { return 1.0f - 2.0f / (1.0f + __expf(2.0f * x)); }

// MFMA, B pinned to AGPR (recurrent weights) / VGPR (input weights)
__device__ __forceinline__ void mfma_a(f32x4& acc, short8 a, short8 b) {
  asm("v_mfma_f32_16x16x32_bf16 %0, %1, %2, %0" : "+v"(acc) : "v"(a), "a"(b));
}
__device__ __forceinline__ void mfma_v(f32x4& acc, short8 a, short8 b) {
  asm("v_mfma_f32_16x16x32_bf16 %0, %1, %2, %0" : "+v"(acc) : "v"(a), "v"(b));
}
// IC-coherent accesses (round-4/9/12/14/16 proven primitives)
__device__ __forceinline__ short8 ld16_ic(const unsigned short* p) {
  union { unsigned long long q[2]; short8 v; } u;
  u.q[0] = __hip_atomic_load((const unsigned long long*)p, __ATOMIC_RELAXED, __HIP_MEMORY_SCOPE_AGENT);
  u.q[1] = __hip_atomic_load(((const unsigned long long*)p) + 1, __ATOMIC_RELAXED, __HIP_MEMORY_SCOPE_AGENT);
  return u.v;
}
__device__ __forceinline__ void st2_ic(unsigned short* p, unsigned short v) {
  unsigned int vv = v;
  asm volatile("global_store_short %0, %1, off sc0 sc1" :: "v"(p), "v"(vv) : "memory");
}
#define POLL(dst, ptr) \
  asm volatile("global_load_dword %0, %1, off sc0 sc1" : "=v"(dst) : "v"(ptr) : "memory")
// full drain: everything retired under ANY vmcnt retirement semantics
#define VMW0() \
  do { asm volatile("s_waitcnt vmcnt(0)" ::: "memory"); \
       __builtin_amdgcn_sched_barrier(0); } while (0)
// sleep-throttled wave-collective flag wait (round-12-proven)
__device__ __forceinline__ void waitN(int* f, int idx, int tgt) {
  for (;;) {
    int v = __hip_atomic_load(&f[idx * 16], __ATOMIC_RELAXED, __HIP_MEMORY_SCOPE_AGENT);
    if (__all(v >= tgt)) break;
    __builtin_amdgcn_s_sleep(1);
  }
}

// ---------------- prep: weight bf16 conversion, bias sums, zero flags ----------------
__global__ void prep_kernel(const float* __restrict__ whh0, const float* __restrict__ wih1,
                            const float* __restrict__ whh1,
                            const float* __restrict__ bih0, const float* __restrict__ bhh0,
                            const float* __restrict__ bih1, const float* __restrict__ bhh1,
                            unsigned short* __restrict__ whh0b, unsigned short* __restrict__ wih1b,
                            unsigned short* __restrict__ whh1b,
                            float* __restrict__ bsum0, float* __restrict__ bsum1,
                            int* __restrict__ flags) {
  int i = blockIdx.x * blockDim.x + threadIdx.x;   // 262144 threads exactly
  if (i < 262144) {
    whh0b[i] = f2bf(whh0[i]);
    wih1b[i] = f2bf(wih1[i]);
    whh1b[i] = f2bf(whh1[i]);
  }
  if (i < 1024) bsum0[i] = bih0[i] + bhh0[i];
  else if (i < 2048) { int j = i - 1024; bsum1[j] = bih1[j] + bhh1[j]; }
  if (i < 8192) flags[i] = 0;
}

// ---------------- fused 2-layer pipeline, quarter-split, per-WAVE flags ----------------
// ROUND-16 byte-for-byte (protocol, flags, targets, rings, arithmetic, spec-poll tail,
// sleep-throttled miss path). One scheduling tweak: L0's x loads hoisted above the MFMA
// block (overlap their L2 latency under the MFMA; r14-proven pattern).
__attribute__((amdgpu_flat_work_group_size(256, 256)))
__attribute__((amdgpu_waves_per_eu(1, 1)))
__global__ void rec_all(
    const float* __restrict__ x,
    const unsigned short* __restrict__ whh0b, const float* __restrict__ wih0,
    const float* __restrict__ bsum0,
    const unsigned short* __restrict__ wih1b,
    const unsigned short* __restrict__ whh1b, const float* __restrict__ bsum1,
    const int* __restrict__ lengths,
    float* __restrict__ pooled,
    unsigned short* __restrict__ h1ring,   // [16][128][256] bf16
    unsigned short* __restrict__ h2ring,   // [2][128][256] bf16
    int* flags)
{
  const int tid = threadIdx.x;
  const int lane = tid & 63;
  const int w = tid >> 6;                  // 0..3
  const int l15 = lane & 15, l4 = lane >> 4;
  const int isL1 = (blockIdx.x >= 32);
  const int wg = blockIdx.x & 31;
  const int q = wg >> 3;
  const int bg = wg & 7;
  const int b0 = bg * 16;
  const int unit = q * 64 + w * 16 + l15;
  const int myfid = (int)blockIdx.x * 4 + w;

  // recurrent weights (AGPR): rows gt*256+unit, K-cols kk*32+l4*8
  const unsigned short* WH = isL1 ? whh1b : whh0b;
  short8 wfh[4][8];
#pragma unroll
  for (int gt = 0; gt < 4; ++gt)
#pragma unroll
    for (int kk = 0; kk < 8; ++kk)
      wfh[gt][kk] = *(const short8*)(WH + (size_t)(gt * 256 + unit) * 256 + kk * 32 + l4 * 8);
  // input weights for L1 (VGPR)
  short8 wfi[4][8];
  if (isL1) {
#pragma unroll
    for (int gt = 0; gt < 4; ++gt)
#pragma unroll
      for (int kk = 0; kk < 8; ++kk)
        wfi[gt][kk] = *(const short8*)(wih1b + (size_t)(gt * 256 + unit) * 256 + kk * 32 + l4 * 8);
  }
  float bs_l[4], wih0_l[4];
#pragma unroll
  for (int gt = 0; gt < 4; ++gt) {
    bs_l[gt] = (isL1 ? bsum1 : bsum0)[gt * 256 + unit];
    wih0_l[gt] = isL1 ? 0.0f : wih0[gt * 256 + unit];
  }

  float c_[4] = {0.f, 0.f, 0.f, 0.f};
  float psum[4] = {0.f, 0.f, 0.f, 0.f};
  int len_[4];
#pragma unroll
  for (int r = 0; r < 4; ++r) len_[r] = lengths[b0 + l4 * 4 + r];

  // loop-carried wait descriptor for step t (initialized for t=0) + speculative state
  int sidx = myfid, stgt = 0, pa = 0;
  if (isL1 && lane < 16) { sidx = ((lane >> 2) * 8 + bg) * 4 + (lane & 3); stgt = 1; }  // h1(0)
  bool hit = false;

  for (int t = 0; t < TT; ++t) {
    // ---- wait for step-t deps (skipped when the speculative poll already hit) ----
    if (!hit) waitN(flags, sidx, stgt);

    f32x4 z = {0.f, 0.f, 0.f, 0.f};
    f32x4 acc[4];
#pragma unroll
    for (int gt = 0; gt < 4; ++gt) acc[gt] = z;

    if (!isL1) {
      // x loads hoisted: overlap L2 latency under the MFMA block
      float xv[4];
#pragma unroll
      for (int r = 0; r < 4; ++r) xv[r] = x[(size_t)(b0 + l4 * 4 + r) * TT + t];

      if (t > 0) {
        const unsigned short* hrow = h1ring + ((size_t)((t - 1) & 15) * BB + b0 + l15) * HH;
        short8 af[8];
#pragma unroll
        for (int kk = 0; kk < 8; ++kk) af[kk] = ld16_ic(hrow + kk * 32 + l4 * 8);
#pragma unroll
        for (int gt = 0; gt < 4; ++gt)
#pragma unroll
          for (int kk = 0; kk < 8; ++kk) mfma_a(acc[gt], af[kk], wfh[gt][kk]);
      }
#pragma unroll
      for (int r = 0; r < 4; ++r) {
        const int sr = l4 * 4 + r;
        float pi = acc[0][r] + bs_l[0] + xv[r] * wih0_l[0];
        float pf = acc[1][r] + bs_l[1] + xv[r] * wih0_l[1];
        float pg = acc[2][r] + bs_l[2] + xv[r] * wih0_l[2];
        float po = acc[3][r] + bs_l[3] + xv[r] * wih0_l[3];
        const float ig = sigm(pi), fg = sigm(pf), gg = tanh_f(pg), og = sigm(po);
        const float cn = fg * c_[r] + ig * gg;
        c_[r] = cn;
        const float hn = og * tanh_f(cn);
        st2_ic(&h1ring[((size_t)(t & 15) * BB + b0 + sr) * HH + unit], f2bf(hn));
      }
    } else {
      // ---- both batch loads issued together (one serialized RTT) ----
      short8 af1[8], af2[8];
      {
        const unsigned short* h1row = h1ring + ((size_t)(t & 15) * BB + b0 + l15) * HH;
#pragma unroll
        for (int kk = 0; kk < 8; ++kk) af1[kk] = ld16_ic(h1row + kk * 32 + l4 * 8);
      }
      if (t > 0) {
        const unsigned short* h2row = h2ring + ((size_t)((t - 1) & 1) * BB + b0 + l15) * HH;
#pragma unroll
        for (int kk = 0; kk < 8; ++kk) af2[kk] = ld16_ic(h2row + kk * 32 + l4 * 8);
      }
#pragma unroll
      for (int gt = 0; gt < 4; ++gt)
#pragma unroll
        for (int kk = 0; kk < 8; ++kk) mfma_v(acc[gt], af1[kk], wfi[gt][kk]);
      if (t > 0) {
#pragma unroll
        for (int gt = 0; gt < 4; ++gt)
#pragma unroll
          for (int kk = 0; kk < 8; ++kk) mfma_a(acc[gt], af2[kk], wfh[gt][kk]);
      }
#pragma unroll
      for (int r = 0; r < 4; ++r) {
        const int sr = l4 * 4 + r;
        float pi = acc[0][r] + bs_l[0];
        float pf = acc[1][r] + bs_l[1];
        float pg = acc[2][r] + bs_l[2];
        float po = acc[3][r] + bs_l[3];
        const float ig = sigm(pi), fg = sigm(pf), gg = tanh_f(pg), og = sigm(po);
        const float cn = fg * c_[r] + ig * gg;
        c_[r] = cn;
        const float hn = og * tanh_f(cn);
        st2_ic(&h2ring[((size_t)(t & 1) * BB + b0 + sr) * HH + unit], f2bf(hn));
        if (t < len_[r]) psum[r] += hn;
      }
    }

    // ---- tail: speculative poll + FULL drain + publish + hit check ----
    {
      const int s = t + 1;
      sidx = myfid; stgt = 0;
      if (s < TT) {
        if (!isL1) {
          if (lane < 16) { sidx = ((lane >> 2) * 8 + bg) * 4 + (lane & 3); stgt = s; }      // h1(s-1)
          else if (lane < 32) {
            if (s >= 16 && (s & 7) == 0) {                                                  // ring credit (depth 16)
              sidx = 128 + (((lane - 16) >> 2) * 8 + bg) * 4 + (lane & 3); stgt = s - 8;
            }
          }
        } else {
          if (lane < 16) { sidx = ((lane >> 2) * 8 + bg) * 4 + (lane & 3); stgt = s + 1; }  // h1(s)
          else if (lane < 32) { sidx = 128 + (((lane - 16) >> 2) * 8 + bg) * 4 + (lane & 3); stgt = s; } // h2(s-1)
        }
      }
      POLL(pa, &flags[sidx * 16]);   // overlaps the store drain
      VMW0();                        // 4 data stores drained AND poll retired (any semantics)
      if (lane == 0)
        __hip_atomic_store(&flags[myfid * 16], s, __ATOMIC_RELAXED, __HIP_MEMORY_SCOPE_AGENT);
      hit = __all(pa >= stgt);
    }
  }

  if (isL1) {
#pragma unroll
    for (int r = 0; r < 4; ++r)
      pooled[(size_t)(b0 + l4 * 4 + r) * HH + unit] = psum[r];
  }
}

// ---------------- epilogue: apply 1/len and linear head ----------------
__global__ void out_kernel(const float* __restrict__ pooled, const int* __restrict__ lengths,
                           const float* __restrict__ wlin, const float* __restrict__ blin,
                           float* __restrict__ out) {
  const int b = blockIdx.x;
  const int lane = threadIdx.x;   // 64
  float s[7];
#pragma unroll
  for (int c = 0; c < 7; ++c) s[c] = 0.f;
  for (int k = lane; k < 256; k += 64) {
    const float pv = pooled[b * 256 + k];
#pragma unroll
    for (int c = 0; c < 7; ++c) s[c] += pv * wlin[c * 256 + k];
  }
#pragma unroll
  for (int c = 0; c < 7; ++c) {
#pragma unroll
    for (int off = 32; off > 0; off >>= 1) s[c] += __shfl_down(s[c], off);
  }
  if (lane == 0) {
    const float inv = 1.0f / (float)lengths[b];
#pragma unroll
    for (int c = 0; c < 7; ++c) out[b * 7 + c] = s[c] * inv + blin[c];
  }
}

extern "C" void kernel_launch(void* const* d_in, const int* in_sizes, int n_in,
                              void* d_out, int out_size, void* d_ws, size_t ws_size,
                              hipStream_t stream) {
  const float* x      = (const float*)d_in[0];
  const int*   lengths= (const int*)d_in[1];
  const float* W_ih0  = (const float*)d_in[2];
  const float* W_hh0  = (const float*)d_in[3];
  const float* b_ih0  = (const float*)d_in[4];
  const float* b_hh0  = (const float*)d_in[5];
  const float* W_ih1  = (const float*)d_in[6];
  const float* W_hh1  = (const float*)d_in[7];
  const float* b_ih1  = (const float*)d_in[8];
  const float* b_hh1  = (const float*)d_in[9];
  const float* W_lin  = (const float*)d_in[10];
  const float* b_lin  = (const float*)d_in[11];
  float* out = (float*)d_out;

  char* ws = (char*)d_ws;
  unsigned short* whh0b = (unsigned short*)(ws + 0);
  unsigned short* wih1b = (unsigned short*)(ws + 524288);
  unsigned short* whh1b = (unsigned short*)(ws + 1048576);
  float* bsum0   = (float*)(ws + 1572864);
  float* bsum1   = (float*)(ws + 1576960);
  int*   flags   = (int*)  (ws + 1581056);                    // 8192 ints (padded flags)
  float* pooled  = (float*)(ws + 1613824);                    // 128KB
  unsigned short* h2ring = (unsigned short*)(ws + 1744896);   // 128KB (depth 2)
  unsigned short* h1ring = (unsigned short*)(ws + 1875968);   // 1MB (depth 16)

  prep_kernel<<<dim3(1024), dim3(256), 0, stream>>>(
      W_hh0, W_ih1, W_hh1, b_ih0, b_hh0, b_ih1, b_hh1,
      whh0b, wih1b, whh1b, bsum0, bsum1, flags);

  rec_all<<<dim3(64), dim3(256), 0, stream>>>(
      x, whh0b, W_ih0, bsum0, wih1b, whh1b, bsum1, lengths,
      pooled, h1ring, h2ring, flags);

  out_kernel<<<dim3(128), dim3(64), 0, stream>>>(pooled, lengths, W_lin, b_lin, out);
}

// Round 19
// 11150.842 us; speedup vs baseline: 1.0729x; 1.0173x over previous
//
#include <hip/hip_runtime.h>
#include <stdint.h>

#define TT 2048
#define HH 256
#define BB 128

typedef __attribute__((ext_vector_type(8))) short short8;   // 8 x bf16 (4 VGPRs)
typedef __attribute__((ext_vector_type(4))) float f32x4;    // 4 x f32 acc

__device__ __forceinline__ unsigned short f2bf(float f) {
  union { float f; unsigned int u; } v; v.f = f;
  unsigned int r = v.u + 0x7fffu + ((v.u >> 16) & 1u);   // RNE
  return (unsigned short)(r >> 16);
}
__device__ __forceinline__ float sigm(float x) { return 1.0f / (1.0f + __expf(-x)); }
__device__ __forceinline__ float tanh_f(float x) { return 1.0f - 2.0f / (1.0f + __expf(2.0f * x)); }

// MFMA, B pinned to AGPR (recurrent weights) / VGPR (input weights)
__device__ __forceinline__ void mfma_a(f32x4& acc, short8 a, short8 b) {
  asm("v_mfma_f32_16x16x32_bf16 %0, %1, %2, %0" : "+v"(acc) : "v"(a), "a"(b));
}
__device__ __forceinline__ void mfma_v(f32x4& acc, short8 a, short8 b) {
  asm("v_mfma_f32_16x16x32_bf16 %0, %1, %2, %0" : "+v"(acc) : "v"(a), "v"(b));
}
// IC-coherent accesses (round-4/9/12/14/16 proven primitives)
__device__ __forceinline__ short8 ld16_ic(const unsigned short* p) {
  union { unsigned long long q[2]; short8 v; } u;
  u.q[0] = __hip_atomic_load((const unsigned long long*)p, __ATOMIC_RELAXED, __HIP_MEMORY_SCOPE_AGENT);
  u.q[1] = __hip_atomic_load(((const unsigned long long*)p) + 1, __ATOMIC_RELAXED, __HIP_MEMORY_SCOPE_AGENT);
  return u.v;
}
__device__ __forceinline__ void st2_ic(unsigned short* p, unsigned short v) {
  unsigned int vv = v;
  asm volatile("global_store_short %0, %1, off sc0 sc1" :: "v"(p), "v"(vv) : "memory");
}
#define POLL(dst, ptr) \
  asm volatile("global_load_dword %0, %1, off sc0 sc1" : "=v"(dst) : "v"(ptr) : "memory")
// full drain: everything retired under ANY vmcnt retirement semantics
#define VMW0() \
  do { asm volatile("s_waitcnt vmcnt(0)" ::: "memory"); \
       __builtin_amdgcn_sched_barrier(0); } while (0)
// sleep-throttled wave-collective flag wait (round-12-proven)
__device__ __forceinline__ void waitN(int* f, int idx, int tgt) {
  for (;;) {
    int v = __hip_atomic_load(&f[idx * 16], __ATOMIC_RELAXED, __HIP_MEMORY_SCOPE_AGENT);
    if (__all(v >= tgt)) break;
    __builtin_amdgcn_s_sleep(1);
  }
}

// ---------------- prep: weight bf16 conversion, bias sums, zero flags ----------------
__global__ void prep_kernel(const float* __restrict__ whh0, const float* __restrict__ wih1,
                            const float* __restrict__ whh1,
                            const float* __restrict__ bih0, const float* __restrict__ bhh0,
                            const float* __restrict__ bih1, const float* __restrict__ bhh1,
                            unsigned short* __restrict__ whh0b, unsigned short* __restrict__ wih1b,
                            unsigned short* __restrict__ whh1b,
                            float* __restrict__ bsum0, float* __restrict__ bsum1,
                            int* __restrict__ flags) {
  int i = blockIdx.x * blockDim.x + threadIdx.x;   // 262144 threads exactly
  if (i < 262144) {
    whh0b[i] = f2bf(whh0[i]);
    wih1b[i] = f2bf(wih1[i]);
    whh1b[i] = f2bf(whh1[i]);
  }
  if (i < 1024) bsum0[i] = bih0[i] + bhh0[i];
  else if (i < 2048) { int j = i - 1024; bsum1[j] = bih1[j] + bhh1[j]; }
  if (i < 8192) flags[i] = 0;
}

// ---------------- fused 2-layer pipeline, quarter-split, per-WAVE flags ----------------
// Final kernel = round-16 (measured best, 11.16 ms): round-14 protocol + speculative
// flag poll fused with the publish drain (POLL -> VMW0 -> publish -> hit check);
// sleep-throttled waitN on miss. Latency-bound: ~2049 serialized cross-CU rendezvous
// on the agent-scope IC path; all faster signaling variants failed verification and
// are quarantined (r6 hang, r10/r11 epochs, r13/r17 poll-rate, r15 partial drain).
__attribute__((amdgpu_flat_work_group_size(256, 256)))
__attribute__((amdgpu_waves_per_eu(1, 1)))
__global__ void rec_all(
    const float* __restrict__ x,
    const unsigned short* __restrict__ whh0b, const float* __restrict__ wih0,
    const float* __restrict__ bsum0,
    const unsigned short* __restrict__ wih1b,
    const unsigned short* __restrict__ whh1b, const float* __restrict__ bsum1,
    const int* __restrict__ lengths,
    float* __restrict__ pooled,
    unsigned short* __restrict__ h1ring,   // [16][128][256] bf16
    unsigned short* __restrict__ h2ring,   // [2][128][256] bf16
    int* flags)
{
  const int tid = threadIdx.x;
  const int lane = tid & 63;
  const int w = tid >> 6;                  // 0..3
  const int l15 = lane & 15, l4 = lane >> 4;
  const int isL1 = (blockIdx.x >= 32);
  const int wg = blockIdx.x & 31;
  const int q = wg >> 3;
  const int bg = wg & 7;
  const int b0 = bg * 16;
  const int unit = q * 64 + w * 16 + l15;
  const int myfid = (int)blockIdx.x * 4 + w;

  // recurrent weights (AGPR): rows gt*256+unit, K-cols kk*32+l4*8
  const unsigned short* WH = isL1 ? whh1b : whh0b;
  short8 wfh[4][8];
#pragma unroll
  for (int gt = 0; gt < 4; ++gt)
#pragma unroll
    for (int kk = 0; kk < 8; ++kk)
      wfh[gt][kk] = *(const short8*)(WH + (size_t)(gt * 256 + unit) * 256 + kk * 32 + l4 * 8);
  // input weights for L1 (VGPR)
  short8 wfi[4][8];
  if (isL1) {
#pragma unroll
    for (int gt = 0; gt < 4; ++gt)
#pragma unroll
      for (int kk = 0; kk < 8; ++kk)
        wfi[gt][kk] = *(const short8*)(wih1b + (size_t)(gt * 256 + unit) * 256 + kk * 32 + l4 * 8);
  }
  float bs_l[4], wih0_l[4];
#pragma unroll
  for (int gt = 0; gt < 4; ++gt) {
    bs_l[gt] = (isL1 ? bsum1 : bsum0)[gt * 256 + unit];
    wih0_l[gt] = isL1 ? 0.0f : wih0[gt * 256 + unit];
  }

  float c_[4] = {0.f, 0.f, 0.f, 0.f};
  float psum[4] = {0.f, 0.f, 0.f, 0.f};
  int len_[4];
#pragma unroll
  for (int r = 0; r < 4; ++r) len_[r] = lengths[b0 + l4 * 4 + r];

  // loop-carried wait descriptor for step t (initialized for t=0) + speculative state
  int sidx = myfid, stgt = 0, pa = 0;
  if (isL1 && lane < 16) { sidx = ((lane >> 2) * 8 + bg) * 4 + (lane & 3); stgt = 1; }  // h1(0)
  bool hit = false;

  for (int t = 0; t < TT; ++t) {
    // ---- wait for step-t deps (skipped when the speculative poll already hit) ----
    if (!hit) waitN(flags, sidx, stgt);

    f32x4 z = {0.f, 0.f, 0.f, 0.f};
    f32x4 acc[4];
#pragma unroll
    for (int gt = 0; gt < 4; ++gt) acc[gt] = z;

    if (!isL1) {
      if (t > 0) {
        const unsigned short* hrow = h1ring + ((size_t)((t - 1) & 15) * BB + b0 + l15) * HH;
        short8 af[8];
#pragma unroll
        for (int kk = 0; kk < 8; ++kk) af[kk] = ld16_ic(hrow + kk * 32 + l4 * 8);
#pragma unroll
        for (int gt = 0; gt < 4; ++gt)
#pragma unroll
          for (int kk = 0; kk < 8; ++kk) mfma_a(acc[gt], af[kk], wfh[gt][kk]);
      }
#pragma unroll
      for (int r = 0; r < 4; ++r) {
        const int sr = l4 * 4 + r;
        const float xv = x[(size_t)(b0 + sr) * TT + t];
        float pi = acc[0][r] + bs_l[0] + xv * wih0_l[0];
        float pf = acc[1][r] + bs_l[1] + xv * wih0_l[1];
        float pg = acc[2][r] + bs_l[2] + xv * wih0_l[2];
        float po = acc[3][r] + bs_l[3] + xv * wih0_l[3];
        const float ig = sigm(pi), fg = sigm(pf), gg = tanh_f(pg), og = sigm(po);
        const float cn = fg * c_[r] + ig * gg;
        c_[r] = cn;
        const float hn = og * tanh_f(cn);
        st2_ic(&h1ring[((size_t)(t & 15) * BB + b0 + sr) * HH + unit], f2bf(hn));
      }
    } else {
      // ---- both batch loads issued together (one serialized RTT) ----
      short8 af1[8], af2[8];
      {
        const unsigned short* h1row = h1ring + ((size_t)(t & 15) * BB + b0 + l15) * HH;
#pragma unroll
        for (int kk = 0; kk < 8; ++kk) af1[kk] = ld16_ic(h1row + kk * 32 + l4 * 8);
      }
      if (t > 0) {
        const unsigned short* h2row = h2ring + ((size_t)((t - 1) & 1) * BB + b0 + l15) * HH;
#pragma unroll
        for (int kk = 0; kk < 8; ++kk) af2[kk] = ld16_ic(h2row + kk * 32 + l4 * 8);
      }
#pragma unroll
      for (int gt = 0; gt < 4; ++gt)
#pragma unroll
        for (int kk = 0; kk < 8; ++kk) mfma_v(acc[gt], af1[kk], wfi[gt][kk]);
      if (t > 0) {
#pragma unroll
        for (int gt = 0; gt < 4; ++gt)
#pragma unroll
          for (int kk = 0; kk < 8; ++kk) mfma_a(acc[gt], af2[kk], wfh[gt][kk]);
      }
#pragma unroll
      for (int r = 0; r < 4; ++r) {
        const int sr = l4 * 4 + r;
        float pi = acc[0][r] + bs_l[0];
        float pf = acc[1][r] + bs_l[1];
        float pg = acc[2][r] + bs_l[2];
        float po = acc[3][r] + bs_l[3];
        const float ig = sigm(pi), fg = sigm(pf), gg = tanh_f(pg), og = sigm(po);
        const float cn = fg * c_[r] + ig * gg;
        c_[r] = cn;
        const float hn = og * tanh_f(cn);
        st2_ic(&h2ring[((size_t)(t & 1) * BB + b0 + sr) * HH + unit], f2bf(hn));
        if (t < len_[r]) psum[r] += hn;
      }
    }

    // ---- tail: speculative poll + FULL drain + publish + hit check ----
    {
      const int s = t + 1;
      sidx = myfid; stgt = 0;
      if (s < TT) {
        if (!isL1) {
          if (lane < 16) { sidx = ((lane >> 2) * 8 + bg) * 4 + (lane & 3); stgt = s; }      // h1(s-1)
          else if (lane < 32) {
            if (s >= 16 && (s & 7) == 0) {                                                  // ring credit (depth 16)
              sidx = 128 + (((lane - 16) >> 2) * 8 + bg) * 4 + (lane & 3); stgt = s - 8;
            }
          }
        } else {
          if (lane < 16) { sidx = ((lane >> 2) * 8 + bg) * 4 + (lane & 3); stgt = s + 1; }  // h1(s)
          else if (lane < 32) { sidx = 128 + (((lane - 16) >> 2) * 8 + bg) * 4 + (lane & 3); stgt = s; } // h2(s-1)
        }
      }
      POLL(pa, &flags[sidx * 16]);   // overlaps the store drain
      VMW0();                        // 4 data stores drained AND poll retired (any semantics)
      if (lane == 0)
        __hip_atomic_store(&flags[myfid * 16], s, __ATOMIC_RELAXED, __HIP_MEMORY_SCOPE_AGENT);
      hit = __all(pa >= stgt);
    }
  }

  if (isL1) {
#pragma unroll
    for (int r = 0; r < 4; ++r)
      pooled[(size_t)(b0 + l4 * 4 + r) * HH + unit] = psum[r];
  }
}

// ---------------- epilogue: apply 1/len and linear head ----------------
__global__ void out_kernel(const float* __restrict__ pooled, const int* __restrict__ lengths,
                           const float* __restrict__ wlin, const float* __restrict__ blin,
                           float* __restrict__ out) {
  const int b = blockIdx.x;
  const int lane = threadIdx.x;   // 64
  float s[7];
#pragma unroll
  for (int c = 0; c < 7; ++c) s[c] = 0.f;
  for (int k = lane; k < 256; k += 64) {
    const float pv = pooled[b * 256 + k];
#pragma unroll
    for (int c = 0; c < 7; ++c) s[c] += pv * wlin[c * 256 + k];
  }
#pragma unroll
  for (int c = 0; c < 7; ++c) {
#pragma unroll
    for (int off = 32; off > 0; off >>= 1) s[c] += __shfl_down(s[c], off);
  }
  if (lane == 0) {
    const float inv = 1.0f / (float)lengths[b];
#pragma unroll
    for (int c = 0; c < 7; ++c) out[b * 7 + c] = s[c] * inv + blin[c];
  }
}

extern "C" void kernel_launch(void* const* d_in, const int* in_sizes, int n_in,
                              void* d_out, int out_size, void* d_ws, size_t ws_size,
                              hipStream_t stream) {
  const float* x      = (const float*)d_in[0];
  const int*   lengths= (const int*)d_in[1];
  const float* W_ih0  = (const float*)d_in[2];
  const float* W_hh0  = (const float*)d_in[3];
  const float* b_ih0  = (const float*)d_in[4];
  const float* b_hh0  = (const float*)d_in[5];
  const float* W_ih1  = (const float*)d_in[6];
  const float* W_hh1  = (const float*)d_in[7];
  const float* b_ih1  = (const float*)d_in[8];
  const float* b_hh1  = (const float*)d_in[9];
  const float* W_lin  = (const float*)d_in[10];
  const float* b_lin  = (const float*)d_in[11];
  float* out = (float*)d_out;

  char* ws = (char*)d_ws;
  unsigned short* whh0b = (unsigned short*)(ws + 0);
  unsigned short* wih1b = (unsigned short*)(ws + 524288);
  unsigned short* whh1b = (unsigned short*)(ws + 1048576);
  float* bsum0   = (float*)(ws + 1572864);
  float* bsum1   = (float*)(ws + 1576960);
  int*   flags   = (int*)  (ws + 1581056);                    // 8192 ints (padded flags)
  float* pooled  = (float*)(ws + 1613824);                    // 128KB
  unsigned short* h2ring = (unsigned short*)(ws + 1744896);   // 128KB (depth 2)
  unsigned short* h1ring = (unsigned short*)(ws + 1875968);   // 1MB (depth 16)

  prep_kernel<<<dim3(1024), dim3(256), 0, stream>>>(
      W_hh0, W_ih1, W_hh1, b_ih0, b_hh0, b_ih1, b_hh1,
      whh0b, wih1b, whh1b, bsum0, bsum1, flags);

  rec_all<<<dim3(64), dim3(256), 0, stream>>>(
      x, whh0b, W_ih0, bsum0, wih1b, whh1b, bsum1, lengths,
      pooled, h1ring, h2ring, flags);

  out_kernel<<<dim3(128), dim3(64), 0, stream>>>(pooled, lengths, W_lin, b_lin, out);
}